// Round 1
// baseline (490.183 us; speedup 1.0000x reference)
//
#include <hip/hip_runtime.h>

#define BB 64
#define CC 8
#define NN 2048
#define TT 64

// Kernel 1: k[b,c,t] = sum_i alpha[i] * x[b,c,i,t]
// One block per (b,c). 256 threads: t4 = float4 index in T (16), ig = i-group (16).
__global__ __launch_bounds__(256) void k_reduce(const float* __restrict__ x,
                                                const float* __restrict__ alpha,
                                                float* __restrict__ kout) {
    const int bc  = blockIdx.x;        // b*C + c
    const int tid = threadIdx.x;
    const int t4  = tid & 15;          // which float4 within T (T=64 -> 16 float4)
    const int ig  = tid >> 4;          // i-group 0..15
    const float4* xp = (const float4*)(x + (size_t)bc * NN * TT);
    float4 acc = make_float4(0.f, 0.f, 0.f, 0.f);
    for (int i = ig; i < NN; i += 16) {
        const float  a = alpha[i];
        const float4 v = xp[i * 16 + t4];
        acc.x += a * v.x; acc.y += a * v.y; acc.z += a * v.z; acc.w += a * v.w;
    }
    __shared__ float4 part[16][16];    // [ig][t4]
    part[ig][t4] = acc;
    __syncthreads();
    for (int s = 8; s > 0; s >>= 1) {
        if (ig < s) {
            const float4 o = part[ig + s][t4];
            acc.x += o.x; acc.y += o.y; acc.z += o.z; acc.w += o.w;
            part[ig][t4] = acc;
        }
        __syncthreads();
    }
    if (ig == 0) {
        ((float4*)(kout + (size_t)bc * TT))[t4] = acc;
    }
}

// Kernel 2: scores[b,c,d] = sum_{t,s} k[b,c,t] * Wc[t,s] * k[b,d,s]; att = softmax_d.
// One block (1 wave, 64 lanes) per batch b.
__global__ __launch_bounds__(64) void att_kernel(const float* __restrict__ kin,
                                                 const float* __restrict__ Wc,
                                                 float* __restrict__ att) {
    const int b = blockIdx.x;
    const int t = threadIdx.x;         // 0..63
    __shared__ float kS[CC][TT];
    __shared__ float mS[CC][TT];
    for (int d = 0; d < CC; ++d)
        kS[d][t] = kin[((size_t)b * CC + d) * TT + t];
    __syncthreads();
    // m[d][t] = sum_s Wc[t][s] * k[d][s]
    float m[CC];
    for (int d = 0; d < CC; ++d) m[d] = 0.f;
    for (int s = 0; s < TT; ++s) {
        const float w = Wc[t * TT + s];
        for (int d = 0; d < CC; ++d) m[d] += w * kS[d][s];
    }
    for (int d = 0; d < CC; ++d) mS[d][t] = m[d];
    __syncthreads();
    // lane -> (c,d) pair; scores[c][d] = sum_t k[c][t] * m[d][t]
    const int c = t >> 3, d = t & 7;
    float sc = 0.f;
    for (int tt = 0; tt < TT; ++tt) sc += kS[c][tt] * mS[d][tt];
    // softmax over d within each 8-lane group (scores sd ~16: subtract max)
    float mx = sc;
    for (int off = 1; off < 8; off <<= 1)
        mx = fmaxf(mx, __shfl_xor(mx, off, 8));
    const float e = __expf(sc - mx);
    float sum = e;
    for (int off = 1; off < 8; off <<= 1)
        sum += __shfl_xor(sum, off, 8);
    att[(size_t)b * CC * CC + t] = e / sum;
}

// Kernel 3: out[b,c,n,t] = sum_i att[b,c,i] * x[b,i,n,t]
// Block covers (b, 16 n-rows). Thread = one float4 of (n,t); 8 loads + 8 stores, all coalesced.
__global__ __launch_bounds__(256) void agg_kernel(const float* __restrict__ x,
                                                  const float* __restrict__ att,
                                                  float* __restrict__ out) {
    const int b     = blockIdx.x >> 7;      // / (N/16 = 128)
    const int ntile = blockIdx.x & 127;
    const int tid   = threadIdx.x;
    __shared__ float attS[CC * CC];
    if (tid < CC * CC) attS[tid] = att[(size_t)b * CC * CC + tid];
    __syncthreads();
    const int n  = ntile * 16 + (tid >> 4);
    const int t4 = tid & 15;
    const size_t base = ((size_t)b * CC * NN + n) * TT + t4 * 4;  // channel 0
    float4 acc[CC];
    for (int c = 0; c < CC; ++c) acc[c] = make_float4(0.f, 0.f, 0.f, 0.f);
    for (int i = 0; i < CC; ++i) {
        const float4 v = *(const float4*)(x + base + (size_t)i * NN * TT);
        for (int c = 0; c < CC; ++c) {
            const float a = attS[c * CC + i];
            acc[c].x += a * v.x; acc[c].y += a * v.y;
            acc[c].z += a * v.z; acc[c].w += a * v.w;
        }
    }
    for (int c = 0; c < CC; ++c)
        *(float4*)(out + base + (size_t)c * NN * TT) = acc[c];
}

extern "C" void kernel_launch(void* const* d_in, const int* in_sizes, int n_in,
                              void* d_out, int out_size, void* d_ws, size_t ws_size,
                              hipStream_t stream) {
    const float* x     = (const float*)d_in[0];   // [B,C,N,T] fp32
    const float* Wc    = (const float*)d_in[1];   // [T,T]
    const float* alpha = (const float*)d_in[2];   // [N]
    float* out = (float*)d_out;                   // [B,C,N,T] fp32

    float* kws   = (float*)d_ws;                  // [B,C,T]   = 128 KiB
    float* attws = kws + (size_t)BB * CC * TT;    // [B,C,C]   = 16 KiB

    k_reduce<<<BB * CC, 256, 0, stream>>>(x, alpha, kws);
    att_kernel<<<BB, 64, 0, stream>>>(kws, Wc, attws);
    agg_kernel<<<BB * (NN / 16), 256, 0, stream>>>(x, attws, out);
}

// Round 3
// 482.535 us; speedup vs baseline: 1.0158x; 1.0158x over previous
//
#include <hip/hip_runtime.h>

#define BB 64
#define CC 8
#define NN 2048
#define TT 64
#define NSPLIT 4
#define NCHUNK (NN / NSPLIT)   // 512

typedef float f4_nt __attribute__((ext_vector_type(4)));  // native vec for nontemporal builtins

// ---------------------------------------------------------------------------
// Pass 1: kp[bc][sp][t] = sum_{i in chunk sp} alpha[i] * x[bc,i,t]
// grid = BB*CC*NSPLIT = 2048 blocks x 256 threads (32 waves/CU for MLP).
// ---------------------------------------------------------------------------
__global__ __launch_bounds__(256) void k_partial(const float* __restrict__ x,
                                                 const float* __restrict__ alpha,
                                                 float* __restrict__ kp) {
    const int bc  = blockIdx.x >> 2;    // 0..511  (b*C + c)
    const int sp  = blockIdx.x & 3;     // N-split 0..3
    const int tid = threadIdx.x;
    const int t4  = tid & 15;           // float4 index within T
    const int ig  = tid >> 4;           // i-group 0..15

    __shared__ float aS[NCHUNK];        // 2 KiB: alpha chunk staged once
    const int i0 = sp * NCHUNK;
    for (int j = tid; j < NCHUNK; j += 256) aS[j] = alpha[i0 + j];
    __syncthreads();

    const float4* xp = (const float4*)(x + ((size_t)bc * NN + i0) * TT);
    float4 acc = make_float4(0.f, 0.f, 0.f, 0.f);
    // 32 iterations; unroll 8 -> 8 independent 1 KiB wave-loads in flight
    #pragma unroll 8
    for (int i = ig; i < NCHUNK; i += 16) {
        const float  a = aS[i];
        const float4 v = xp[i * 16 + t4];
        acc.x = fmaf(a, v.x, acc.x);
        acc.y = fmaf(a, v.y, acc.y);
        acc.z = fmaf(a, v.z, acc.z);
        acc.w = fmaf(a, v.w, acc.w);
    }

    __shared__ float4 part[16][16];     // [ig][t4]; 2-way bank alias = free
    part[ig][t4] = acc;
    __syncthreads();
    for (int s = 8; s > 0; s >>= 1) {
        if (ig < s) {
            const float4 o = part[ig + s][t4];
            acc.x += o.x; acc.y += o.y; acc.z += o.z; acc.w += o.w;
            part[ig][t4] = acc;
        }
        __syncthreads();
    }
    if (ig == 0)
        ((float4*)(kp + ((size_t)bc * NSPLIT + sp) * TT))[t4] = acc;
}

// ---------------------------------------------------------------------------
// Pass 2: per batch b — sum split partials -> k[8][64]; m = Wc-weighted k;
// scores = k . m ; softmax over d -> att[b][8][8].
// grid = 64 blocks x 256 threads. Wc staged TRANSPOSED (+pad) to avoid the
// 64-way column-read bank conflict.
// ---------------------------------------------------------------------------
__global__ __launch_bounds__(256) void att_kernel(const float* __restrict__ kp,
                                                  const float* __restrict__ Wc,
                                                  float* __restrict__ att) {
    const int b   = blockIdx.x;
    const int tid = threadIdx.x;

    __shared__ float wT[TT][TT + 1];    // wT[s][t] = Wc[t][s]
    __shared__ float kS[CC][TT + 1];
    __shared__ float mS[CC][TT + 1];

    // coalesced float4 load of Wc, scattered transpose into padded LDS
    for (int idx = tid; idx < TT * TT / 4; idx += 256) {
        const float4 w = ((const float4*)Wc)[idx];
        const int t = idx >> 4;          // row of Wc
        const int s = (idx & 15) * 4;    // col of Wc
        wT[s + 0][t] = w.x;
        wT[s + 1][t] = w.y;
        wT[s + 2][t] = w.z;
        wT[s + 3][t] = w.w;
    }
    // sum the NSPLIT partials -> k
    for (int idx = tid; idx < CC * TT; idx += 256) {
        const int c = idx >> 6, t = idx & 63;
        float s = 0.f;
        #pragma unroll
        for (int sp = 0; sp < NSPLIT; ++sp)
            s += kp[(((size_t)b * CC + c) * NSPLIT + sp) * TT + t];
        kS[c][t] = s;
    }
    __syncthreads();

    // m[d][t] = sum_s Wc[t][s] * k[d][s] = sum_s wT[s][t] * kS[d][s]
    for (int idx = tid; idx < CC * TT; idx += 256) {
        const int d = idx >> 6, t = idx & 63;
        float acc = 0.f;
        #pragma unroll 8
        for (int s = 0; s < TT; ++s)
            acc = fmaf(wT[s][t], kS[d][s], acc);   // wT: 2-way alias; kS: broadcast
        mS[d][t] = acc;
    }
    __syncthreads();

    // scores[c][d] = sum_t k[c][t]*m[d][t]; softmax over d (8-lane groups)
    if (tid < 64) {
        const int c = tid >> 3, d = tid & 7;
        float sc = 0.f;
        #pragma unroll 8
        for (int t = 0; t < TT; ++t)
            sc = fmaf(kS[c][t], mS[d][t], sc);
        float mx = sc;
        for (int off = 1; off < 8; off <<= 1)
            mx = fmaxf(mx, __shfl_xor(mx, off, 8));
        const float e = __expf(sc - mx);
        float sum = e;
        for (int off = 1; off < 8; off <<= 1)
            sum += __shfl_xor(sum, off, 8);
        att[(size_t)b * CC * CC + tid] = e / sum;
    }
}

// ---------------------------------------------------------------------------
// Pass 3: out[b,c,n,t] = sum_i att[b,c,i] * x[b,i,n,t]
// grid = BB*(NN/16) = 8192 blocks x 256 threads. 8 coalesced 1 KiB wave-loads
// + 8 nontemporal 1 KiB wave-stores (keep x resident in L3 for this pass).
// ---------------------------------------------------------------------------
__global__ __launch_bounds__(256) void agg_kernel(const float* __restrict__ x,
                                                  const float* __restrict__ att,
                                                  float* __restrict__ out) {
    const int b     = blockIdx.x >> 7;
    const int ntile = blockIdx.x & 127;
    const int tid   = threadIdx.x;

    __shared__ float attS[CC * CC];
    if (tid < CC * CC) attS[tid] = att[(size_t)b * CC * CC + tid];
    __syncthreads();

    const int n  = ntile * 16 + (tid >> 4);
    const int t4 = tid & 15;
    const size_t base = ((size_t)b * CC * NN + n) * TT + t4 * 4;

    float4 v[CC];
    #pragma unroll
    for (int i = 0; i < CC; ++i)
        v[i] = *(const float4*)(x + base + (size_t)i * NN * TT);

    float4 acc[CC];
    #pragma unroll
    for (int c = 0; c < CC; ++c) acc[c] = make_float4(0.f, 0.f, 0.f, 0.f);
    #pragma unroll
    for (int i = 0; i < CC; ++i) {
        #pragma unroll
        for (int c = 0; c < CC; ++c) {
            const float a = attS[c * CC + i];
            acc[c].x = fmaf(a, v[i].x, acc[c].x);
            acc[c].y = fmaf(a, v[i].y, acc[c].y);
            acc[c].z = fmaf(a, v[i].z, acc[c].z);
            acc[c].w = fmaf(a, v[i].w, acc[c].w);
        }
    }
    #pragma unroll
    for (int c = 0; c < CC; ++c) {
        f4_nt val = { acc[c].x, acc[c].y, acc[c].z, acc[c].w };
        __builtin_nontemporal_store(val, (f4_nt*)(out + base + (size_t)c * NN * TT));
    }
}

extern "C" void kernel_launch(void* const* d_in, const int* in_sizes, int n_in,
                              void* d_out, int out_size, void* d_ws, size_t ws_size,
                              hipStream_t stream) {
    const float* x     = (const float*)d_in[0];   // [B,C,N,T] fp32
    const float* Wc    = (const float*)d_in[1];   // [T,T]
    const float* alpha = (const float*)d_in[2];   // [N]
    float* out = (float*)d_out;

    float* kpws  = (float*)d_ws;                         // [B*C][NSPLIT][T] = 512 KiB
    float* attws = kpws + (size_t)BB * CC * NSPLIT * TT; // [B][C][C] = 16 KiB

    k_partial<<<BB * CC * NSPLIT, 256, 0, stream>>>(x, alpha, kpws);
    att_kernel<<<BB, 256, 0, stream>>>(kpws, Wc, attws);
    agg_kernel<<<BB * (NN / 16), 256, 0, stream>>>(x, attws, out);
}